// Round 23
// baseline (128.051 us; speedup 1.0000x reference)
//
#include <hip/hip_runtime.h>
#include <math.h>

#define NBATCH 8192
#define NNODE  25
#define DIN    256
#define NH     8
#define NF     32
#define HF     256
#define NE     48
#define NT     73     // NE + NNODE self loops
#define NEG_SLOPE 0.2f

// d_ws: [0,139264) bf16 Waug frags (17*8*64*8 shorts);
//       [139264, +4096) f32 lnm[32][32]: log(edge multiplicity), -1e30 if absent
#define WS_LNM_OFF 139264

typedef __bf16 bf16x8 __attribute__((ext_vector_type(8)));
typedef float  f32x4  __attribute__((ext_vector_type(4)));

static __device__ __forceinline__ unsigned short f2bf(float f) {
    unsigned int u = __float_as_uint(f);
    return (unsigned short)((u + 0x7fffu + ((u >> 16) & 1u)) >> 16);
}

static __device__ __forceinline__ float bpermf(int idxb, float v) {
    return __int_as_float(__builtin_amdgcn_ds_bpermute(idxb, __float_as_int(v)));
}

// ---- prep: pack Waug B-frags (verified r2-r22) + lnm table (verified r6-r22) ----
__global__ void prep(const float* __restrict__ W,
                     const float* __restrict__ a_src,
                     const float* __restrict__ a_dst,
                     const int*   __restrict__ edges,
                     unsigned short* __restrict__ wf,
                     float* __restrict__ lnm) {
    const int blk = blockIdx.x;
    if (blk < 34) {
        const int tid  = blk * 256 + threadIdx.x;   // 0..8703 == 17*8*64
        const int lane = tid & 63;
        const int ks   = (tid >> 6) & 7;
        const int ct   = tid >> 9;
        const int k0   = ks * 32 + (lane >> 4) * 8;
        if (ct < 16) {
            const int col = ct * 16 + (lane & 15);
#pragma unroll
            for (int j = 0; j < 8; ++j)
                wf[tid * 8 + j] = f2bf(W[(k0 + j) * HF + col]);
        } else {
            // tile 16: Waug[k][0..7]=W·a_src per head, [8..15]=W·a_dst per head.
            const int hp = lane & 15;
            const float* av = (hp < 8) ? (a_src + hp * NF) : (a_dst + (hp - 8) * NF);
            const int wc = (hp & 7) * NF;
#pragma unroll
            for (int j = 0; j < 8; ++j) {
                float s = 0.f;
                for (int f = 0; f < NF; ++f)
                    s = fmaf(W[(k0 + j) * HF + wc + f], av[f], s);
                wf[tid * 8 + j] = f2bf(s);
            }
        }
    } else {
        // dense log-multiplicity adjacency: lnm[d][s]
        __shared__ int cnt[32 * 32];
        const int t = threadIdx.x;
        for (int i = t; i < 1024; i += 256) cnt[i] = 0;
        __syncthreads();
        if (t < NT) {
            const int s = (t < NE) ? edges[t]      : (t - NE);
            const int d = (t < NE) ? edges[NE + t] : (t - NE);
            atomicAdd(&cnt[d * 32 + s], 1);
        }
        __syncthreads();
        for (int i = t; i < 1024; i += 256) {
            const int c = cnt[i];
            lnm[i] = (c > 0) ? logf((float)c) : -1e30f;
        }
    }
}

// ---- main: r20 structure, but af (X A-frags, 64 regs) moved to a wave-
//      private swizzled LDS tile + lnm reloaded per head, targeting TOTAL
//      (VGPR+AGPR unified) <= 128 => the 4-waves/SIMD occupancy tier
//      (m69 tiers: alloc <=128 -> 16 waves/CU). Depth-2 wf prefetch KEPT
//      (r17: losing it costs more than +1 wave gains). NT stores kept.
//      af LDS swizzle: granule g^(row&7) -> wave64 ds_read_b128 hits each
//      4-bank group with 8 lanes = the 8-pass minimum (bank-optimal). ----
__global__ __launch_bounds__(256, 4)
void gat_wave(const float* __restrict__ X,
              const unsigned short* __restrict__ wf,
              const float* __restrict__ lnm,
              const float* __restrict__ bias,
              float* __restrict__ out)
{
    __shared__ __align__(16) unsigned char sAF[4][16384];   // per-wave af tile [32 rows][512 B]
    __shared__ __align__(16) unsigned char sTile[4][2048];  // per-wave GEMM2 h-tile dbuf
    const int t   = threadIdx.x;
    const int w   = t >> 6;
    const int l   = t & 63;
    const int b   = blockIdx.x * 4 + w;
    unsigned char* myAF = sAF[w];
    unsigned char* myT  = sTile[w];
    const int r   = l & 15;
    const int kq  = l >> 4;
    const int kqa = kq & 1;
    const bool hiSel = (kq >> 1) != 0;   // m-half of src index s = kq*8+j (softmax)

    // bpermute byte-index bases (r8-verified, softmax only)
    const int idx_as_base = kqa * 32;            // + (h>>2)*64 + 4j
    const int idx_ad_base = 128 + r * 4;         // + (h>>2)*64

    // GEMM2 h-tile LDS addresses (r16-verified)
    const int wrA = r * 64 + ((kq ^ (r & 6)) << 3);
    const int wrB = r * 64 + (((4 + kq) ^ (r & 6)) << 3);
    const int rdA = r * 64 + (((2 * kq) ^ (r & 6)) << 3);

    // ---- stage X -> myAF (bf16, granule-swizzled). lane l: row = l&31,
    //      granules (l>>5)*16 .. +15 (granule = 16 B = 8 bf16 = 8 k). ----
    {
        const int row = l & 31;
        const int g0  = (l >> 5) * 16;
        const int rx  = row & 7;
        if (row < NNODE) {
            const float* xr = X + (size_t)b * (NNODE * DIN) + row * DIN;
#pragma unroll
            for (int i = 0; i < 16; ++i) {
                const int g = g0 + i;
                const f32x4 x0 = *(const f32x4*)(xr + g * 8);
                const f32x4 x1 = *(const f32x4*)(xr + g * 8 + 4);
                bf16x8 v;
                v[0]=(__bf16)x0[0]; v[1]=(__bf16)x0[1]; v[2]=(__bf16)x0[2]; v[3]=(__bf16)x0[3];
                v[4]=(__bf16)x1[0]; v[5]=(__bf16)x1[1]; v[6]=(__bf16)x1[2]; v[7]=(__bf16)x1[3];
                *(bf16x8*)(myAF + row * 512 + ((g ^ rx) << 4)) = v;
            }
        } else {
            const uint4 z = make_uint4(0, 0, 0, 0);
#pragma unroll
            for (int i = 0; i < 16; ++i) {
                const int g = g0 + i;
                *(uint4*)(myAF + row * 512 + ((g ^ rx) << 4)) = z;
            }
        }
    }
    __syncthreads();   // af tiles ready (cheap: once per kernel)

    const int afX   = r & 7;              // xor value (== (16+r)&7)
    const int afB0  = r * 512;            // row r base
    const int afB1  = (16 + r) * 512;     // row 16+r base

    // ---- logits, swapped: accL{m}[q] = L[16m+r][head-col 4kq+q] ----
    f32x4 accL0 = {0.f, 0.f, 0.f, 0.f};
    f32x4 accL1 = {0.f, 0.f, 0.f, 0.f};
#pragma unroll
    for (int ks = 0; ks < 8; ++ks) {
        const int gx = ((ks * 4 + kq) ^ afX) << 4;
        const bf16x8 a0f = *(const bf16x8*)(myAF + afB0 + gx);
        const bf16x8 a1f = *(const bf16x8*)(myAF + afB1 + gx);
        const bf16x8 wa  = *(const bf16x8*)(wf + ((size_t)(128 + ks) * 64 + l) * 8);
        accL0 = __builtin_amdgcn_mfma_f32_16x16x32_bf16(wa, a0f, accL0, 0, 0, 0);
        accL1 = __builtin_amdgcn_mfma_f32_16x16x32_bf16(wa, a1f, accL1, 0, 0, 0);
    }

    // ---- prefetch B-frags for tiles 0 (even buf) and 1 (odd buf) ----
    bf16x8 bwE[8], bwO[8];
#pragma unroll
    for (int ks = 0; ks < 8; ++ks)
        bwE[ks] = *(const bf16x8*)(wf + ((size_t)(0 * 8 + ks) * 64 + l) * 8);
#pragma unroll
    for (int ks = 0; ks < 8; ++ks)
        bwO[ks] = *(const bf16x8*)(wf + ((size_t)(1 * 8 + ks) * 64 + l) * 8);

    float* ob = out + (size_t)b * (NNODE * HF);

#pragma unroll
    for (int h = 0; h < 8; ++h) {
        // ---- adjacency log-mults reloaded per head (L2-hot; frees 16 regs) ----
        const f32x4 lnA0 = *(const f32x4*)(lnm + r * 32 + kq * 8);
        const f32x4 lnA1 = *(const f32x4*)(lnm + r * 32 + kq * 8 + 4);
        const f32x4 lnB0 = *(const f32x4*)(lnm + (16 + r) * 32 + kq * 8);
        const f32x4 lnB1 = *(const f32x4*)(lnm + (16 + r) * 32 + kq * 8 + 4);

        // ---- softmax for head h (r8-verified) ----
        const int hb2 = (h >> 2) * 64;
        const int q   = h & 3;                      // static after unroll
        const float ad0 = bpermf(idx_ad_base + hb2, accL0[q]);   // L[d=r][8+h]
        const float ad1 = bpermf(idx_ad_base + hb2, accL1[q]);   // L[d=16+r][8+h]
        float e0[8], e1[8];
        float s0 = 0.f, s1 = 0.f;
#pragma unroll
        for (int j = 0; j < 8; ++j) {
            const int ia = idx_as_base + hb2 + j * 4;
            const float v0 = bpermf(ia, accL0[q]);
            const float v1 = bpermf(ia, accL1[q]);
            const float asj = hiSel ? v1 : v0;      // as[s = kq*8+j][h]
            const float ln0j = (j < 4) ? lnA0[j & 3] : lnA1[j & 3];
            const float ln1j = (j < 4) ? lnB0[j & 3] : lnB1[j & 3];
            float t0 = asj + ad0; t0 = (t0 > 0.f) ? t0 : NEG_SLOPE * t0;
            float t1 = asj + ad1; t1 = (t1 > 0.f) ? t1 : NEG_SLOPE * t1;
            e0[j] = __expf(t0 + ln0j);              // mult * exp(leaky), 0 if no edge
            e1[j] = __expf(t1 + ln1j);
            s0 += e0[j]; s1 += e1[j];
        }
        s0 += __shfl_xor(s0, 16); s0 += __shfl_xor(s0, 32);
        s1 += __shfl_xor(s1, 16); s1 += __shfl_xor(s1, 32);
        const float i0 = 1.f / (s0 + 1e-16f);
        const float i1 = 1.f / (s1 + 1e-16f);
        // pf{m}: lane(r,kq)[j] = alpha[dst 16m+r][src kq*8+j]  (A/B-frag layout)
        bf16x8 pf0, pf1;
#pragma unroll
        for (int j = 0; j < 8; ++j) {
            pf0[j] = (__bf16)(e0[j] * i0);
            pf1[j] = (__bf16)(e1[j] * i1);
        }

        // ---- two 16-col feature tiles of this head ----
#pragma unroll
        for (int cc = 0; cc < 2; ++cc) {
            const int ct = 2 * h + cc;
            const bf16x8* bw = cc ? bwO : bwE;
            // GEMM1: h columns ct*16..+15; A-frags re-read from swizzled LDS.
            f32x4 a0 = {0.f, 0.f, 0.f, 0.f};
            f32x4 a1 = {0.f, 0.f, 0.f, 0.f};
#pragma unroll
            for (int ks = 0; ks < 8; ++ks) {
                const int gx = ((ks * 4 + kq) ^ afX) << 4;
                const bf16x8 af0k = *(const bf16x8*)(myAF + afB0 + gx);
                const bf16x8 af1k = *(const bf16x8*)(myAF + afB1 + gx);
                a0 = __builtin_amdgcn_mfma_f32_16x16x32_bf16(af0k, bw[ks], a0, 0, 0, 0);
                a1 = __builtin_amdgcn_mfma_f32_16x16x32_bf16(af1k, bw[ks], a1, 0, 0, 0);
            }
            if (h < 7) {   // prefetch tile ct+2 into the buffer just consumed
                bf16x8* dst = cc ? bwO : bwE;
#pragma unroll
                for (int ks = 0; ks < 8; ++ks)
                    dst[ks] = *(const bf16x8*)(wf + ((size_t)((ct + 2) * 8 + ks) * 64 + l) * 8);
            }
            // ---- h-tile -> LDS (bf16, swizzled) -> GEMM2 B-frag (r16-verified) ----
            unsigned char* buf = myT + ((ct & 1) << 10);
            {
                const unsigned int lo0 = (unsigned int)f2bf(a0[0]) | ((unsigned int)f2bf(a0[1]) << 16);
                const unsigned int hi0 = (unsigned int)f2bf(a0[2]) | ((unsigned int)f2bf(a0[3]) << 16);
                const unsigned int lo1 = (unsigned int)f2bf(a1[0]) | ((unsigned int)f2bf(a1[1]) << 16);
                const unsigned int hi1 = (unsigned int)f2bf(a1[2]) | ((unsigned int)f2bf(a1[3]) << 16);
                *(uint2*)(buf + wrA) = make_uint2(lo0, hi0);   // nodes 4kq..+3   of col r
                *(uint2*)(buf + wrB) = make_uint2(lo1, hi1);   // nodes 16+4kq..+3
            }
            const bf16x8 hb = *(const bf16x8*)(buf + rdA);     // h[8kq..8kq+7][ct*16+r]

            // GEMM2, swapped (r18-verified): D = h^T · P^T = out^T tile.
            // D[row = feat-in-tile 4kq+q'][col = dst r]; non-temporal stores (r20).
            const f32x4 bv = *(const f32x4*)(bias + ct * 16 + kq * 4);
            f32x4 o0 = bv, o1 = bv;
            o0 = __builtin_amdgcn_mfma_f32_16x16x32_bf16(hb, pf0, o0, 0, 0, 0);
            o1 = __builtin_amdgcn_mfma_f32_16x16x32_bf16(hb, pf1, o1, 0, 0, 0);
            __builtin_nontemporal_store(o0, (f32x4*)(ob + r * HF + ct * 16 + kq * 4));
            if (r < 9)
                __builtin_nontemporal_store(o1, (f32x4*)(ob + (16 + r) * HF + ct * 16 + kq * 4));
        }
    }
}

extern "C" void kernel_launch(void* const* d_in, const int* in_sizes, int n_in,
                              void* d_out, int out_size, void* d_ws, size_t ws_size,
                              hipStream_t stream) {
    const float* X     = (const float*)d_in[0];
    const float* W     = (const float*)d_in[1];
    const float* a_src = (const float*)d_in[2];
    const float* a_dst = (const float*)d_in[3];
    const float* bias  = (const float*)d_in[4];
    const int*   edges = (const int*)d_in[5];
    float* out = (float*)d_out;
    unsigned short* wf = (unsigned short*)d_ws;
    float* lnm = (float*)((unsigned char*)d_ws + WS_LNM_OFF);

    hipLaunchKernelGGL(prep, dim3(35), dim3(256), 0, stream,
                       W, a_src, a_dst, edges, wf, lnm);
    hipLaunchKernelGGL(gat_wave, dim3(NBATCH / 4), dim3(256), 0, stream,
                       X, wf, lnm, bias, out);
}

// Round 24
// 119.563 us; speedup vs baseline: 1.0710x; 1.0710x over previous
//
#include <hip/hip_runtime.h>
#include <math.h>

#define NBATCH 8192
#define NNODE  25
#define DIN    256
#define NH     8
#define NF     32
#define HF     256
#define NE     48
#define NT     73     // NE + NNODE self loops
#define NEG_SLOPE 0.2f

// d_ws: [0,139264) bf16 Waug frags (17*8*64*8 shorts);
//       [139264, +4096) f32 lnm[32][32]: log(edge multiplicity), -1e30 if absent
#define WS_LNM_OFF 139264

typedef __bf16 bf16x8 __attribute__((ext_vector_type(8)));
typedef float  f32x4  __attribute__((ext_vector_type(4)));

static __device__ __forceinline__ unsigned short f2bf(float f) {
    unsigned int u = __float_as_uint(f);
    return (unsigned short)((u + 0x7fffu + ((u >> 16) & 1u)) >> 16);
}

static __device__ __forceinline__ float bpermf(int idxb, float v) {
    return __int_as_float(__builtin_amdgcn_ds_bpermute(idxb, __float_as_int(v)));
}

// ---- prep: pack Waug B-frags (verified r2-r23) + lnm table (verified r6-r23) ----
__global__ void prep(const float* __restrict__ W,
                     const float* __restrict__ a_src,
                     const float* __restrict__ a_dst,
                     const int*   __restrict__ edges,
                     unsigned short* __restrict__ wf,
                     float* __restrict__ lnm) {
    const int blk = blockIdx.x;
    if (blk < 34) {
        const int tid  = blk * 256 + threadIdx.x;   // 0..8703 == 17*8*64
        const int lane = tid & 63;
        const int ks   = (tid >> 6) & 7;
        const int ct   = tid >> 9;
        const int k0   = ks * 32 + (lane >> 4) * 8;
        if (ct < 16) {
            const int col = ct * 16 + (lane & 15);
#pragma unroll
            for (int j = 0; j < 8; ++j)
                wf[tid * 8 + j] = f2bf(W[(k0 + j) * HF + col]);
        } else {
            // tile 16: Waug[k][0..7]=W·a_src per head, [8..15]=W·a_dst per head.
            const int hp = lane & 15;
            const float* av = (hp < 8) ? (a_src + hp * NF) : (a_dst + (hp - 8) * NF);
            const int wc = (hp & 7) * NF;
#pragma unroll
            for (int j = 0; j < 8; ++j) {
                float s = 0.f;
                for (int f = 0; f < NF; ++f)
                    s = fmaf(W[(k0 + j) * HF + wc + f], av[f], s);
                wf[tid * 8 + j] = f2bf(s);
            }
        }
    } else {
        // dense log-multiplicity adjacency: lnm[d][s]
        __shared__ int cnt[32 * 32];
        const int t = threadIdx.x;
        for (int i = t; i < 1024; i += 256) cnt[i] = 0;
        __syncthreads();
        if (t < NT) {
            const int s = (t < NE) ? edges[t]      : (t - NE);
            const int d = (t < NE) ? edges[NE + t] : (t - NE);
            atomicAdd(&cnt[d * 32 + s], 1);
        }
        __syncthreads();
        for (int i = t; i < 1024; i += 256) {
            const int c = cnt[i];
            lnm[i] = (c > 0) ? logf((float)c) : -1e30f;
        }
    }
}

// ---- main: r20 EXACT REVERT (session best, 121.7 us).
//      Cached X loads (r21: nt loads regress) + depth-2 wf register
//      prefetch (r15) + LDS h-tile round-trip (r16) + swapped GEMM2 with
//      f32x4 stores (r18) + NON-TEMPORAL output stores (r20, -16%:
//      write-once stream no longer evicts wf/X from L2). 2 waves/SIMD is
//      the register-file-imposed optimum (r17/r19/r23 all regress). ----
__global__ __launch_bounds__(256, 2)
void gat_wave(const float* __restrict__ X,
              const unsigned short* __restrict__ wf,
              const float* __restrict__ lnm,
              const float* __restrict__ bias,
              float* __restrict__ out)
{
    __shared__ __align__(16) unsigned char sTile[8192];   // 4 waves x 2KB (2x1KB dbuf)
    const int t   = threadIdx.x;
    const int l   = t & 63;
    const int b   = blockIdx.x * 4 + (t >> 6);
    unsigned char* myT = sTile + (t >> 6) * 2048;
    const int r   = l & 15;
    const int kq  = l >> 4;
    const int kqa = kq & 1;
    const bool hiSel = (kq >> 1) != 0;   // m-half of src index s = kq*8+j (softmax)

    // bpermute byte-index bases (r8-verified, softmax only)
    const int idx_as_base = kqa * 32;            // + (h>>2)*64 + 4j
    const int idx_ad_base = 128 + r * 4;         // + (h>>2)*64

    // LDS tile addresses (byte offsets within the 1KB buffer), r16-verified:
    const int wrA = r * 64 + ((kq ^ (r & 6)) << 3);
    const int wrB = r * 64 + (((4 + kq) ^ (r & 6)) << 3);
    const int rdA = r * 64 + (((2 * kq) ^ (r & 6)) << 3);

    // ---- A-frags straight from global (cached): af{m}[ks] = X[16m+r][ks*32+kq*8 ..+7] ----
    bf16x8 af0[8], af1[8];
    const float* Xb = X + (size_t)b * (NNODE * DIN);
    {
        const float* xp0 = Xb + r * DIN + kq * 8;
#pragma unroll
        for (int ks = 0; ks < 8; ++ks) {
            const f32x4 x0 = *(const f32x4*)(xp0 + ks * 32);
            const f32x4 x1 = *(const f32x4*)(xp0 + ks * 32 + 4);
            bf16x8 v;
            v[0]=(__bf16)x0[0]; v[1]=(__bf16)x0[1]; v[2]=(__bf16)x0[2]; v[3]=(__bf16)x0[3];
            v[4]=(__bf16)x1[0]; v[5]=(__bf16)x1[1]; v[6]=(__bf16)x1[2]; v[7]=(__bf16)x1[3];
            af0[ks] = v;
        }
        const bool valid = r < 9;                 // rows 16+r must be < 25
        const float zm = valid ? 1.f : 0.f;
        const float* xp1 = Xb + (valid ? (16 + r) : r) * DIN + kq * 8;
#pragma unroll
        for (int ks = 0; ks < 8; ++ks) {
            const f32x4 x0 = *(const f32x4*)(xp1 + ks * 32);
            const f32x4 x1 = *(const f32x4*)(xp1 + ks * 32 + 4);
            bf16x8 v;
            v[0]=(__bf16)(x0[0]*zm); v[1]=(__bf16)(x0[1]*zm); v[2]=(__bf16)(x0[2]*zm); v[3]=(__bf16)(x0[3]*zm);
            v[4]=(__bf16)(x1[0]*zm); v[5]=(__bf16)(x1[1]*zm); v[6]=(__bf16)(x1[2]*zm); v[7]=(__bf16)(x1[3]*zm);
            af1[ks] = v;
        }
    }

    // ---- logits, swapped: accL{m}[q] = L[16m+r][head-col 4kq+q] ----
    f32x4 accL0 = {0.f, 0.f, 0.f, 0.f};
    f32x4 accL1 = {0.f, 0.f, 0.f, 0.f};
#pragma unroll
    for (int ks = 0; ks < 8; ++ks) {
        const bf16x8 wa = *(const bf16x8*)(wf + ((size_t)(128 + ks) * 64 + l) * 8);
        accL0 = __builtin_amdgcn_mfma_f32_16x16x32_bf16(wa, af0[ks], accL0, 0, 0, 0);
        accL1 = __builtin_amdgcn_mfma_f32_16x16x32_bf16(wa, af1[ks], accL1, 0, 0, 0);
    }

    // ---- adjacency log-mults resident: lnm[d=dstt*16+r][s=kq*8+j] ----
    const f32x4 lnA0 = *(const f32x4*)(lnm + r * 32 + kq * 8);
    const f32x4 lnA1 = *(const f32x4*)(lnm + r * 32 + kq * 8 + 4);
    const f32x4 lnB0 = *(const f32x4*)(lnm + (16 + r) * 32 + kq * 8);
    const f32x4 lnB1 = *(const f32x4*)(lnm + (16 + r) * 32 + kq * 8 + 4);

    // ---- prefetch B-frags for tiles 0 (even buf) and 1 (odd buf) ----
    bf16x8 bwE[8], bwO[8];
#pragma unroll
    for (int ks = 0; ks < 8; ++ks)
        bwE[ks] = *(const bf16x8*)(wf + ((size_t)(0 * 8 + ks) * 64 + l) * 8);
#pragma unroll
    for (int ks = 0; ks < 8; ++ks)
        bwO[ks] = *(const bf16x8*)(wf + ((size_t)(1 * 8 + ks) * 64 + l) * 8);

    float* ob = out + (size_t)b * (NNODE * HF);

#pragma unroll
    for (int h = 0; h < 8; ++h) {
        // ---- softmax for head h (r8-verified) ----
        const int hb2 = (h >> 2) * 64;
        const int q   = h & 3;                      // static after unroll
        const float ad0 = bpermf(idx_ad_base + hb2, accL0[q]);   // L[d=r][8+h]
        const float ad1 = bpermf(idx_ad_base + hb2, accL1[q]);   // L[d=16+r][8+h]
        float e0[8], e1[8];
        float s0 = 0.f, s1 = 0.f;
#pragma unroll
        for (int j = 0; j < 8; ++j) {
            const int ia = idx_as_base + hb2 + j * 4;
            const float v0 = bpermf(ia, accL0[q]);
            const float v1 = bpermf(ia, accL1[q]);
            const float asj = hiSel ? v1 : v0;      // as[s = kq*8+j][h]
            const float ln0j = (j < 4) ? lnA0[j & 3] : lnA1[j & 3];
            const float ln1j = (j < 4) ? lnB0[j & 3] : lnB1[j & 3];
            float t0 = asj + ad0; t0 = (t0 > 0.f) ? t0 : NEG_SLOPE * t0;
            float t1 = asj + ad1; t1 = (t1 > 0.f) ? t1 : NEG_SLOPE * t1;
            e0[j] = __expf(t0 + ln0j);              // mult * exp(leaky), 0 if no edge
            e1[j] = __expf(t1 + ln1j);
            s0 += e0[j]; s1 += e1[j];
        }
        s0 += __shfl_xor(s0, 16); s0 += __shfl_xor(s0, 32);
        s1 += __shfl_xor(s1, 16); s1 += __shfl_xor(s1, 32);
        const float i0 = 1.f / (s0 + 1e-16f);
        const float i1 = 1.f / (s1 + 1e-16f);
        // pf{m}: lane(r,kq)[j] = alpha[dst 16m+r][src kq*8+j]  (A/B-frag layout)
        bf16x8 pf0, pf1;
#pragma unroll
        for (int j = 0; j < 8; ++j) {
            pf0[j] = (__bf16)(e0[j] * i0);
            pf1[j] = (__bf16)(e1[j] * i1);
        }

        // ---- two 16-col feature tiles of this head ----
#pragma unroll
        for (int cc = 0; cc < 2; ++cc) {
            const int ct = 2 * h + cc;
            const bf16x8* bw = cc ? bwO : bwE;
            // GEMM1: h columns ct*16..+15. acc{m}[q'] = h[16m+4kq+q'][ct*16+r]
            f32x4 a0 = {0.f, 0.f, 0.f, 0.f};
            f32x4 a1 = {0.f, 0.f, 0.f, 0.f};
#pragma unroll
            for (int ks = 0; ks < 8; ++ks) {
                a0 = __builtin_amdgcn_mfma_f32_16x16x32_bf16(af0[ks], bw[ks], a0, 0, 0, 0);
                a1 = __builtin_amdgcn_mfma_f32_16x16x32_bf16(af1[ks], bw[ks], a1, 0, 0, 0);
            }
            if (h < 7) {   // prefetch tile ct+2 into the buffer just consumed
                bf16x8* dst = cc ? bwO : bwE;
#pragma unroll
                for (int ks = 0; ks < 8; ++ks)
                    dst[ks] = *(const bf16x8*)(wf + ((size_t)((ct + 2) * 8 + ks) * 64 + l) * 8);
            }
            // ---- h-tile -> LDS (bf16, swizzled) -> GEMM2 B-frag (r16-verified) ----
            unsigned char* buf = myT + ((ct & 1) << 10);
            {
                const unsigned int lo0 = (unsigned int)f2bf(a0[0]) | ((unsigned int)f2bf(a0[1]) << 16);
                const unsigned int hi0 = (unsigned int)f2bf(a0[2]) | ((unsigned int)f2bf(a0[3]) << 16);
                const unsigned int lo1 = (unsigned int)f2bf(a1[0]) | ((unsigned int)f2bf(a1[1]) << 16);
                const unsigned int hi1 = (unsigned int)f2bf(a1[2]) | ((unsigned int)f2bf(a1[3]) << 16);
                *(uint2*)(buf + wrA) = make_uint2(lo0, hi0);   // nodes 4kq..+3   of col r
                *(uint2*)(buf + wrB) = make_uint2(lo1, hi1);   // nodes 16+4kq..+3
            }
            const bf16x8 hb = *(const bf16x8*)(buf + rdA);     // h[8kq..8kq+7][ct*16+r]

            // GEMM2, swapped (r18-verified): D = h^T · P^T = out^T tile.
            // D[row = feat-in-tile 4kq+q'][col = dst r]; non-temporal stores (r20).
            const f32x4 bv = *(const f32x4*)(bias + ct * 16 + kq * 4);
            f32x4 o0 = bv, o1 = bv;
            o0 = __builtin_amdgcn_mfma_f32_16x16x32_bf16(hb, pf0, o0, 0, 0, 0);
            o1 = __builtin_amdgcn_mfma_f32_16x16x32_bf16(hb, pf1, o1, 0, 0, 0);
            __builtin_nontemporal_store(o0, (f32x4*)(ob + r * HF + ct * 16 + kq * 4));
            if (r < 9)
                __builtin_nontemporal_store(o1, (f32x4*)(ob + (16 + r) * HF + ct * 16 + kq * 4));
        }
    }
}

extern "C" void kernel_launch(void* const* d_in, const int* in_sizes, int n_in,
                              void* d_out, int out_size, void* d_ws, size_t ws_size,
                              hipStream_t stream) {
    const float* X     = (const float*)d_in[0];
    const float* W     = (const float*)d_in[1];
    const float* a_src = (const float*)d_in[2];
    const float* a_dst = (const float*)d_in[3];
    const float* bias  = (const float*)d_in[4];
    const int*   edges = (const int*)d_in[5];
    float* out = (float*)d_out;
    unsigned short* wf = (unsigned short*)d_ws;
    float* lnm = (float*)((unsigned char*)d_ws + WS_LNM_OFF);

    hipLaunchKernelGGL(prep, dim3(35), dim3(256), 0, stream,
                       W, a_src, a_dst, edges, wf, lnm);
    hipLaunchKernelGGL(gat_wave, dim3(NBATCH / 4), dim3(256), 0, stream,
                       X, wf, lnm, bias, out);
}